// Round 1
// baseline (124.857 us; speedup 1.0000x reference)
//
#include <hip/hip_runtime.h>
#include <math.h>

#define B_SZ 1024
#define N_SZ 128
#define M_SZ 256
#define I_SZ 64

// One block per sample b, one thread per hidden unit m.
// Running prefix z replaces the [B,M,N] cumsum tensor.
// normal^2 = 4*P0^2 + 2*Pw0^2 + 2*Pw1^2  (ALLCFG offsets [0,0,0,w1,w0,0,w0,w1])
// psi1 product over i is separable per (m,i) -> single end reduction.
__global__ __launch_bounds__(256) void arrbm_kernel(
    const float* __restrict__ vis,     // [B,N]
    const float* __restrict__ hb,      // [M]
    const float* __restrict__ weight,  // [M,N]
    float* __restrict__ out)           // [B]
{
    const int b    = blockIdx.x;
    const int m    = threadIdx.x;   // 0..255
    const int lane = m & 63;
    const int wave = m >> 6;        // 0..3

    __shared__ float s_vis[N_SZ];
    __shared__ float s_part[4][3];
    __shared__ float s_psi[4];

    if (m < N_SZ) s_vis[m] = vis[b * N_SZ + m];
    __syncthreads();

    const float  bias = hb[m];
    const float* wrow = weight + (size_t)m * N_SZ;

    float z         = 0.0f;   // running prefix sum_{k<2i} v_k * w_k
    float psi_local = 1.0f;   // per-thread product of cos(full) over i
    float acc       = 1.0f;   // thread 0: product of 1/normal_i

    for (int i = 0; i < I_SZ; ++i) {
        float w0 = wrow[2 * i];
        float w1 = wrow[2 * i + 1];
        float v0 = s_vis[2 * i];
        float v1 = s_vis[2 * i + 1];

        float pre  = bias + z;
        float step = v0 * w0 + v1 * w1;
        z += step;

        psi_local *= __cosf(pre + step);

        float p0  = __cosf(pre);
        float pw0 = __cosf(pre + w0);
        float pw1 = __cosf(pre + w1);

        // wave-level product reduction (64 lanes)
        #pragma unroll
        for (int off = 32; off >= 1; off >>= 1) {
            p0  *= __shfl_xor(p0,  off, 64);
            pw0 *= __shfl_xor(pw0, off, 64);
            pw1 *= __shfl_xor(pw1, off, 64);
        }
        if (lane == 0) {
            s_part[wave][0] = p0;
            s_part[wave][1] = pw0;
            s_part[wave][2] = pw1;
        }
        __syncthreads();
        if (m == 0) {
            float P0  = s_part[0][0] * s_part[1][0] * s_part[2][0] * s_part[3][0];
            float Pw0 = s_part[0][1] * s_part[1][1] * s_part[2][1] * s_part[3][1];
            float Pw1 = s_part[0][2] * s_part[1][2] * s_part[2][2] * s_part[3][2];
            float n2  = 4.0f * P0 * P0 + 2.0f * Pw0 * Pw0 + 2.0f * Pw1 * Pw1;
            acc *= rsqrtf(n2);
        }
        __syncthreads();  // protect s_part for next iteration
    }

    // block-level product reduction of psi_local
    #pragma unroll
    for (int off = 32; off >= 1; off >>= 1)
        psi_local *= __shfl_xor(psi_local, off, 64);
    if (lane == 0) s_psi[wave] = psi_local;
    __syncthreads();

    if (m == 0) {
        float psi = s_psi[0] * s_psi[1] * s_psi[2] * s_psi[3];
        // Sz == 0 filter: sz = 0.5 * sum(v_even - v_odd)
        float sz = 0.0f;
        for (int i = 0; i < I_SZ; ++i)
            sz += 0.5f * (s_vis[2 * i] - s_vis[2 * i + 1]);
        float res = psi * acc;
        out[b] = (sz != 0.0f) ? 0.0f : res;
    }
}

extern "C" void kernel_launch(void* const* d_in, const int* in_sizes, int n_in,
                              void* d_out, int out_size, void* d_ws, size_t ws_size,
                              hipStream_t stream) {
    const float* vis    = (const float*)d_in[0];  // [B,N]
    const float* hb     = (const float*)d_in[1];  // [M]
    const float* weight = (const float*)d_in[2];  // [M,N]
    float* out = (float*)d_out;                   // [B]

    arrbm_kernel<<<B_SZ, M_SZ, 0, stream>>>(vis, hb, weight, out);
}

// Round 2
// 96.181 us; speedup vs baseline: 1.2981x; 1.2981x over previous
//
#include <hip/hip_runtime.h>
#include <math.h>

#define B_SZ 1024
#define N_SZ 128
#define M_SZ 256
#define I_SZ 64
#define CH   16            // i-chunk batched into registers
#define NCH  (I_SZ / CH)

// One block = one wave (64 lanes) per sample b. Lane owns m = lane + {0,64,128,192}.
// Running prefix z_m replaces the [B,M,N] cumsum. Reductions over m are pure
// wave butterflies (no LDS, no barriers). normal^2 = 4*P0^2 + 2*Pw0^2 + 2*Pw1^2.
// psi1 reuses p0 of the next iteration: cos(full_i) == cos(pre_{i+1}).
__global__ __launch_bounds__(64) void arrbm_kernel(
    const float* __restrict__ vis,     // [B,N]
    const float* __restrict__ hb,      // [M]
    const float* __restrict__ weight,  // [M,N]
    float* __restrict__ out)           // [B]
{
    const int b    = blockIdx.x;
    const int lane = threadIdx.x;      // 0..63

    __shared__ float s_vis[N_SZ];
    ((float2*)s_vis)[lane] = ((const float2*)(vis + (size_t)b * N_SZ))[lane];
    __syncthreads();

    float bias[4], z[4];
    const float2* wp[4];
    #pragma unroll
    for (int mm = 0; mm < 4; ++mm) {
        const int m = lane + mm * 64;
        bias[mm] = hb[m];
        z[mm]    = 0.0f;
        wp[mm]   = (const float2*)(weight + (size_t)m * N_SZ);
    }

    float psi = 1.0f;   // product of cos(pre) over i>=0 (corrected at end)
    float acc = 1.0f;   // product of 1/normal_i

    for (int ic = 0; ic < NCH; ++ic) {
        float r0[CH], r1[CH], r2[CH];
        #pragma unroll
        for (int j = 0; j < CH; ++j) {
            const int   i  = ic * CH + j;
            const float v0 = s_vis[2 * i];
            const float v1 = s_vis[2 * i + 1];
            float q0 = 1.0f, q1 = 1.0f, q2 = 1.0f;
            #pragma unroll
            for (int mm = 0; mm < 4; ++mm) {
                const float2 w   = wp[mm][i];
                const float  pre = bias[mm] + z[mm];
                const float  c0  = __cosf(pre);
                q0 *= c0;
                q1 *= __cosf(pre + w.x);
                q2 *= __cosf(pre + w.y);
                psi *= c0;                       // includes spurious i=0 term, fixed later
                z[mm] += v0 * w.x + v1 * w.y;
            }
            r0[j] = q0; r1[j] = q1; r2[j] = q2;
        }
        // 3*CH independent butterfly product-reductions — chains pipeline
        #pragma unroll
        for (int j = 0; j < CH; ++j) {
            #pragma unroll
            for (int off = 32; off >= 1; off >>= 1) {
                r0[j] *= __shfl_xor(r0[j], off, 64);
                r1[j] *= __shfl_xor(r1[j], off, 64);
                r2[j] *= __shfl_xor(r2[j], off, 64);
            }
            acc *= rsqrtf(4.0f * r0[j] * r0[j] + 2.0f * r1[j] * r1[j] + 2.0f * r2[j] * r2[j]);
        }
    }

    // psi currently = prod_i cos(pre_i) = prod cos(full_{-1..62}); fix the ends:
    // drop cos(pre_0)=cos(bias), add cos(full_63)=cos(bias+z_total), per m.
    #pragma unroll
    for (int mm = 0; mm < 4; ++mm)
        psi *= __cosf(bias[mm] + z[mm]) / __cosf(bias[mm]);

    // reduce psi across lanes (product)
    #pragma unroll
    for (int off = 32; off >= 1; off >>= 1)
        psi *= __shfl_xor(psi, off, 64);

    // Sz==0 filter: sum of (v_even - v_odd)
    float szl = s_vis[2 * lane] - s_vis[2 * lane + 1];
    #pragma unroll
    for (int off = 32; off >= 1; off >>= 1)
        szl += __shfl_xor(szl, off, 64);

    if (lane == 0)
        out[b] = (szl != 0.0f) ? 0.0f : psi * acc;
}

extern "C" void kernel_launch(void* const* d_in, const int* in_sizes, int n_in,
                              void* d_out, int out_size, void* d_ws, size_t ws_size,
                              hipStream_t stream) {
    const float* vis    = (const float*)d_in[0];  // [B,N]
    const float* hb     = (const float*)d_in[1];  // [M]
    const float* weight = (const float*)d_in[2];  // [M,N]
    float* out = (float*)d_out;                   // [B]

    arrbm_kernel<<<B_SZ, 64, 0, stream>>>(vis, hb, weight, out);
}